// Round 11
// baseline (46.952 us; speedup 1.0000x reference)
//
#include <hip/hip_runtime.h>
#include <math.h>

#define CDIM   862
#define NRANK  8
#define KW     7
#define ROWS_PER_BLOCK 4
#define THREADS (ROWS_PER_BLOCK * 64)
#define LN_EPS 1e-5f
#define EPL    14            // elements per lane: 62 lanes cover 862 (lane 61 partial)
#define PPL    (EPL / 2)     // 7 output float2 pairs per lane
#define NQ     11            // window float2 loads per lane: x[14i-4 .. 14i+17]
#define MAXPAIR 430          // last valid float2 pair index in a row (862/2 - 1)

// One wave = one row; lane i owns elements [14i, 14i+13] from a 22-float
// register window (no LDS, no barriers). THIS ROUND: phase-batched compute
// inside each element-pair -- all 16 conv chains interleaved (k outermost),
// then 16 z+exp back-to-back, then the 8 rcp+combine -- to force the
// scheduler to overlap the 16 independent dependency chains (round 10
// showed ~15% per-wave issue duty with near-serial emission at VGPR=52).
// Arithmetic identical per chain -> absmax must stay 0.03125.
__global__ __launch_bounds__(THREADS, 4) void cvmc_kernel(
    const float* __restrict__ x,
    const float* __restrict__ Wup,
    const float* __restrict__ bup,
    const float* __restrict__ Wdown,
    const float* __restrict__ bdown,
    const float* __restrict__ gamma,
    const float* __restrict__ beta,
    float* __restrict__ out)
{
    const int lane = threadIdx.x & 63;
    const int wv   = threadIdx.x >> 6;
    const int row  = blockIdx.x * ROWS_PER_BLOCK + wv;

    // Uniform weights -> SGPR scalar loads.
    float wu[NRANK][KW];
    float bu[NRANK], wd[NRANK];
#pragma unroll
    for (int r = 0; r < NRANK; ++r) {
#pragma unroll
        for (int k = 0; k < KW; ++k) wu[r][k] = Wup[r * KW + k];
        bu[r] = bup[r];
        wd[r] = Wdown[r];
    }
    const float bd = bdown[0];

    const float C1 = -0.0713548162f;   // gelu(t) ~ t*sigmoid(1.5957691 t + 0.07135482 t^3)
    const float C0 = -1.5957691216f;

    const float2* __restrict__ xp = reinterpret_cast<const float2*>(x + (size_t)row * CDIM);

    // Load the lane's 22-float window into registers (indices static after unroll).
    float w[2 * NQ];
#pragma unroll
    for (int q = 0; q < NQ; ++q) {
        int pi = 7 * lane - 2 + q;                 // float2 pair index (may be OOB)
        int pc = pi < 0 ? 0 : (pi > MAXPAIR ? MAXPAIR : pi);
        float2 v = xp[pc];
        // Left halo x[-4..-1]: lane 0, q<2. Right halo x[862..]: lane 61, q>=6.
        if (q < 2)  { if (lane == 0)  { v.x = 0.0f; v.y = 0.0f; } }
        if (q >= 6) { if (lane == 61) { v.x = 0.0f; v.y = 0.0f; } }
        w[2 * q]     = v.x;
        w[2 * q + 1] = v.y;
    }

    float2 yv[PPL];
    float sum = 0.0f, sumsq = 0.0f;

#pragma unroll
    for (int pe = 0; pe < PPL; ++pe) {
        const int ce = EPL * lane + 2 * pe;        // global element index of y0
        const bool valid = (ce < CDIM);            // pairs never split (862 even)
        const int f = 2 * pe;                      // elem0 window = w[f+1..f+7], elem1 = w[f+2..f+8]

        // ---- Phase A: all 16 conv chains, k outermost (16-way interleave) ----
        float t[2 * NRANK];                        // t[2r+e], e in {0,1}
#pragma unroll
        for (int r = 0; r < NRANK; ++r) {
            t[2 * r]     = bu[r];
            t[2 * r + 1] = bu[r];
        }
#pragma unroll
        for (int k = 0; k < KW; ++k) {
#pragma unroll
            for (int r = 0; r < NRANK; ++r) {
                t[2 * r]     = fmaf(wu[r][k], w[f + k + 1], t[2 * r]);
                t[2 * r + 1] = fmaf(wu[r][k], w[f + k + 2], t[2 * r + 1]);
            }
        }

        // ---- Phase B+C: all 16 z and exp back-to-back (trans pipe saturated) ----
        float u[2 * NRANK];                        // u = 1 + exp(z)
#pragma unroll
        for (int i = 0; i < 2 * NRANK; ++i) {
            const float tt = t[i];
            const float z  = tt * fmaf(tt * tt, C1, C0);
            u[i] = 1.0f + __expf(z);
        }

        // ---- Phase D: rank-paired rcp + combine (same order as rounds 6-10) ----
        float acc0 = bd, acc1 = bd;
#pragma unroll
        for (int rp = 0; rp < NRANK / 2; ++rp) {
            const int ia0 = 4 * rp, ia1 = 4 * rp + 1;   // rank 2rp,   elem 0/1
            const int ib0 = 4 * rp + 2, ib1 = 4 * rp + 3; // rank 2rp+1, elem 0/1
            const float r0 = __builtin_amdgcn_rcpf(u[ia0] * u[ib0]);
            const float r1 = __builtin_amdgcn_rcpf(u[ia1] * u[ib1]);
            const float aa0 = wd[2 * rp] * t[ia0],     aa1 = wd[2 * rp] * t[ia1];
            const float ab0 = wd[2 * rp + 1] * t[ib0], ab1 = wd[2 * rp + 1] * t[ib1];
            float n0 = aa0 * u[ib0]; n0 = fmaf(ab0, u[ia0], n0);
            float n1 = aa1 * u[ib1]; n1 = fmaf(ab1, u[ia1], n1);
            acc0 = fmaf(n0, r0, acc0);
            acc1 = fmaf(n1, r1, acc1);
        }

        float y0 = w[f + 4] + acc0;   // x[ce]   + h
        float y1 = w[f + 5] + acc1;   // x[ce+1] + h
        if (!valid) { y0 = 0.0f; y1 = 0.0f; }      // tail lanes contribute 0
        yv[pe] = make_float2(y0, y1);
        sum += y0 + y1;
        sumsq = fmaf(y0, y0, sumsq);
        sumsq = fmaf(y1, y1, sumsq);
    }

    // In-wave butterfly: every lane ends with row totals. No LDS, no barrier.
#pragma unroll
    for (int off = 1; off < 64; off <<= 1) {
        sum   += __shfl_xor(sum, off, 64);
        sumsq += __shfl_xor(sumsq, off, 64);
    }

    {
        const float inv  = 1.0f / (float)CDIM;
        const float mu   = sum * inv;
        const float var  = fmaf(sumsq, inv, -mu * mu);
        const float rstd = rsqrtf(var + LN_EPS);

        float2* __restrict__ yr2 = reinterpret_cast<float2*>(out + (size_t)row * CDIM);
        const float2* __restrict__ g2 = reinterpret_cast<const float2*>(gamma);
        const float2* __restrict__ b2 = reinterpret_cast<const float2*>(beta);
#pragma unroll
        for (int pe = 0; pe < PPL; ++pe) {
            const int ce = EPL * lane + 2 * pe;
            if (ce < CDIM) {
                const int m = 7 * lane + pe;       // pair index in row
                const float2 gv = g2[m];
                const float2 bv = b2[m];
                float2 o;
                o.x = fmaf((yv[pe].x - mu) * rstd, gv.x, bv.x);
                o.y = fmaf((yv[pe].y - mu) * rstd, gv.y, bv.y);
                yr2[m] = o;
            }
        }
    }
}

extern "C" void kernel_launch(void* const* d_in, const int* in_sizes, int n_in,
                              void* d_out, int out_size, void* d_ws, size_t ws_size,
                              hipStream_t stream) {
    const float* x     = (const float*)d_in[0];
    const float* Wup   = (const float*)d_in[1];
    const float* bup   = (const float*)d_in[2];
    const float* Wdown = (const float*)d_in[3];
    const float* bdown = (const float*)d_in[4];
    const float* gamma = (const float*)d_in[5];
    const float* beta  = (const float*)d_in[6];
    float* out = (float*)d_out;

    const int nrows = out_size / CDIM;                 // 11520 (divisible by 4)
    const int nblk  = nrows / ROWS_PER_BLOCK;          // 2880
    cvmc_kernel<<<nblk, THREADS, 0, stream>>>(x, Wup, bup, Wdown, bdown,
                                              gamma, beta, out);
}